// Round 16
// baseline (299.244 us; speedup 1.0000x reference)
//
#include <hip/hip_runtime.h>
#include <hip/hip_bf16.h>

#define NROWS 8192
#define NITER 10
#define ESCALE 1048576.0f          // 2^20 fixed-point scale for E partials
#define EINV   (1.0f / 1048576.0f)

typedef __attribute__((ext_vector_type(8))) short bf16x8;
typedef __attribute__((ext_vector_type(8))) unsigned short u16x8;
typedef __attribute__((ext_vector_type(16))) float f32x16;

__device__ __forceinline__ float bf2f(unsigned short u) {
  union { float f; unsigned int i; } c; c.i = ((unsigned int)u) << 16; return c.f;
}
__device__ __forceinline__ unsigned short f2bf(float f) {
  unsigned int x = __float_as_uint(f);
  unsigned int r = (x + 0x7FFFu + ((x >> 16) & 1u)) >> 16;
  return (unsigned short)r;
}

// tril inversion, 128-wide grid (64x64 tiles) for ppbuild
#define TRIS(b) ((b) * (257 - (b)) / 2)
__device__ __forceinline__ void tril_decode(int L, int& bi, int& bj) {
  int b = (int)((257.0f - sqrtf((float)(66049 - 8 * L))) * 0.5f);
  if (b > 127) b = 127;
  if (b < 0) b = 0;
  while (b < 127 && TRIS(b + 1) <= L) ++b;
  while (b > 0 && TRIS(b) > L) --b;
  bi = b;
  bj = b + (L - TRIS(b));
}

// tril inversion, 64-wide grid (128x128 tiles) for ppmv
#define TRIS64(b) ((b) * (129 - (b)) / 2)
__device__ __forceinline__ void tril64_decode(int L, int& bi, int& bj) {
  int b = (int)((129.0f - sqrtf((float)(16641 - 8 * L))) * 0.5f);
  if (b > 63) b = 63;
  if (b < 0) b = 0;
  while (b < 63 && TRIS64(b + 1) <= L) ++b;
  while (b > 0 && TRIS64(b) > L) --b;
  bi = b;
  bj = b + (L - TRIS64(b));
}

// casts x, W1, W2 to bf16 (8 elems/thread) and zeroes Z0 (it-1 accumulator)
__global__ __launch_bounds__(256) void cast3(const float* __restrict__ x,
                                             const float* __restrict__ W1,
                                             const float* __restrict__ W2,
                                             unsigned short* __restrict__ xb,
                                             unsigned short* __restrict__ w1b,
                                             unsigned short* __restrict__ w2b,
                                             unsigned long long* __restrict__ Z0) {
  int idx = blockIdx.x * 256 + threadIdx.x;
  if (idx < NROWS) Z0[idx] = 0ull;
  const float* src; unsigned short* dst; int l;
  if (idx < 131072) { src = x; dst = xb; l = idx; }
  else if (idx < 139264) { src = W1; dst = w1b; l = idx - 131072; }
  else if (idx < 155648) { src = W2; dst = w2b; l = idx - 139264; }
  else return;
  const float4* p = (const float4*)src + (size_t)l * 2;
  float4 a = p[0], b = p[1];
  u16x8 o;
  o[0] = f2bf(a.x); o[1] = f2bf(a.y); o[2] = f2bf(a.z); o[3] = f2bf(a.w);
  o[4] = f2bf(b.x); o[5] = f2bf(b.y); o[6] = f2bf(b.z); o[7] = f2bf(b.w);
  *(u16x8*)(dst + (size_t)l * 8) = o;
}

// C[M,NN] = A[M,K] @ B[NN,K]^T (bf16 in, bf16 out) + fused per-column
// partial BN stats. If abA != null, the A operand is transformed
// leaky_relu(a*v+b) during staging (fuses the previous bn_apply kernel;
// identical fp32 op order -> bit-identical values).
__global__ __launch_bounds__(256) void gemm_bt_mfma_stats(
    const unsigned short* __restrict__ A, const unsigned short* __restrict__ B,
    const float2* __restrict__ abA,
    unsigned short* __restrict__ Cb, float* __restrict__ pS, float* __restrict__ pQ,
    int NN, int K) {
  __shared__ __align__(16) unsigned short Asw[4096];
  __shared__ __align__(16) unsigned short Bsw[4096];
  __shared__ float Sarr[4][64], Qarr[4][64];
  __shared__ float2 abLds[512];
  const int i0 = blockIdx.x * 64, j0 = blockIdx.y * 64;
  const int t = threadIdx.x;
  const int lane = t & 63;
  const int wv = t >> 6;
  const int wi = wv >> 1, wj = wv & 1;
  const int khalf = lane >> 5;

  if (abA) {
    abLds[t] = abA[t];
    if (t + 256 < K) abLds[t + 256] = abA[t + 256];
  }

  f32x16 acc;
#pragma unroll
  for (int r = 0; r < 16; ++r) acc[r] = 0.f;

  const int lrow = t >> 2;
  const int lgp = (t & 3) * 2;
  const int arow = wi * 32 + (lane & 31);
  const int brow = wj * 32 + (lane & 31);
  const int nc = K >> 6;
#pragma unroll 1
  for (int c = 0; c < nc; ++c) {
    const unsigned short* sa = A + (size_t)(i0 + lrow) * K + c * 64 + lgp * 8;
    const unsigned short* sb = B + (size_t)(j0 + lrow) * K + c * 64 + lgp * 8;
    u16x8 va0 = *(const u16x8*)(sa);
    u16x8 va1 = *(const u16x8*)(sa + 8);
    u16x8 vb0 = *(const u16x8*)(sb);
    u16x8 vb1 = *(const u16x8*)(sb + 8);
    __syncthreads();
    if (abA) {  // fused BN+leaky on the A operand (wave-uniform branch)
      int cb0 = c * 64 + lgp * 8;
#pragma unroll
      for (int k = 0; k < 8; ++k) {
        float2 a0 = abLds[cb0 + k];
        float2 a1 = abLds[cb0 + 8 + k];
        float r0 = a0.x * bf2f((unsigned short)va0[k]) + a0.y;
        float r1 = a1.x * bf2f((unsigned short)va1[k]) + a1.y;
        r0 = r0 >= 0.f ? r0 : 0.01f * r0;
        r1 = r1 >= 0.f ? r1 : 0.01f * r1;
        va0[k] = (unsigned short)f2bf(r0);
        va1[k] = (unsigned short)f2bf(r1);
      }
    }
    int s0 = (lgp ^ (lrow & 7)) * 8;
    int s1 = ((lgp + 1) ^ (lrow & 7)) * 8;
    *(u16x8*)&Asw[lrow * 64 + s0] = va0;
    *(u16x8*)&Asw[lrow * 64 + s1] = va1;
    *(u16x8*)&Bsw[lrow * 64 + s0] = vb0;
    *(u16x8*)&Bsw[lrow * 64 + s1] = vb1;
    __syncthreads();
#pragma unroll
    for (int s = 0; s < 4; ++s) {
      int slot = s * 2 + khalf;
      bf16x8 a = *(const bf16x8*)&Asw[arow * 64 + ((slot ^ (arow & 7)) * 8)];
      bf16x8 b = *(const bf16x8*)&Bsw[brow * 64 + ((slot ^ (brow & 7)) * 8)];
      acc = __builtin_amdgcn_mfma_f32_32x32x16_bf16(a, b, acc, 0, 0, 0);
    }
  }
  // epilogue: bf16 store + per-lane column stats (16 rows of column coll)
  float s = 0.f, q = 0.f;
#pragma unroll
  for (int r = 0; r < 16; ++r) {
    int rowl = (r & 3) + 8 * (r >> 2) + 4 * khalf;
    int coll = lane & 31;
    float v = acc[r];
    s += v; q += v * v;
    Cb[(size_t)(i0 + wi * 32 + rowl) * NN + j0 + wj * 32 + coll] = f2bf(v);
  }
  Sarr[wv][lane] = s;
  Qarr[wv][lane] = q;
  __syncthreads();
  if (t < 64) {  // column c of block: fold 4 deterministic contributions
    int wjc = t >> 5, coll = t & 31;
    float st = (Sarr[wjc][coll] + Sarr[wjc][coll + 32]) +
               (Sarr[wjc + 2][coll] + Sarr[wjc + 2][coll + 32]);
    float qt = (Qarr[wjc][coll] + Qarr[wjc][coll + 32]) +
               (Qarr[wjc + 2][coll] + Qarr[wjc + 2][coll + 32]);
    pS[(size_t)blockIdx.x * NN + j0 + t] = st;
    pQ[(size_t)blockIdx.x * NN + j0 + t] = qt;
  }
}

// fold 128 row-block partial stats -> per-column scale/shift
__global__ void bn_finalize(const float* __restrict__ pS, const float* __restrict__ pQ,
                            const float* __restrict__ g, const float* __restrict__ be,
                            float2* __restrict__ ab, int C) {
  int c = blockIdx.x * 256 + threadIdx.x;
  if (c >= C) return;
  float s = 0.f, q = 0.f;
  for (int r = 0; r < 128; ++r) { s += pS[(size_t)r * C + c]; q += pQ[(size_t)r * C + c]; }
  const float invM = 1.f / 8192.f;
  float mu = s * invM;
  float var = q * invM - mu * mu;
  float rstd = rsqrtf(var + 1e-5f);
  float a = g[c] * rstd;
  ab[c] = make_float2(a, be[c] - mu * a);
}

// fused: feats-BN + leaky + row norm + fc logit; writes fnorm bf16, unary, coef0
__global__ __launch_bounds__(256) void bn_rowfn(const unsigned short* __restrict__ fraw,
                                                const float2* __restrict__ ab,
                                                const float* __restrict__ fcw,
                                                const float* __restrict__ fcb,
                                                unsigned short* __restrict__ fnorm,
                                                float* __restrict__ unary,
                                                float* __restrict__ coef0) {
  const int lane = threadIdx.x & 63;
  const int row = blockIdx.x * 4 + (threadIdx.x >> 6);
  ushort4 v4 = *(const ushort4*)(fraw + (size_t)row * 256 + lane * 4);
  float4 w = *(const float4*)(fcw + lane * 4);
  int c = lane * 4;
  float2 a0 = ab[c], a1 = ab[c + 1], a2 = ab[c + 2], a3 = ab[c + 3];
  float f0 = a0.x * bf2f(v4.x) + a0.y; f0 = f0 >= 0.f ? f0 : 0.01f * f0;
  float f1 = a1.x * bf2f(v4.y) + a1.y; f1 = f1 >= 0.f ? f1 : 0.01f * f1;
  float f2 = a2.x * bf2f(v4.z) + a2.y; f2 = f2 >= 0.f ? f2 : 0.01f * f2;
  float f3 = a3.x * bf2f(v4.w) + a3.y; f3 = f3 >= 0.f ? f3 : 0.01f * f3;
  float ssq = f0 * f0 + f1 * f1 + f2 * f2 + f3 * f3;
  float dot = f0 * w.x + f1 * w.y + f2 * w.z + f3 * w.w;
#pragma unroll
  for (int o = 32; o; o >>= 1) { ssq += __shfl_xor(ssq, o); dot += __shfl_xor(dot, o); }
  float rfn = rsqrtf(ssq);
  *(ushort4*)(fnorm + (size_t)row * 256 + lane * 4) =
      make_ushort4(f2bf(f0 * rfn), f2bf(f1 * rfn), f2bf(f2 * rfn), f2bf(f3 * rfn));
  if (lane == 0) {
    float lg = dot + fcb[0];
    unary[row] = lg;
    coef0[row] = 1.f - 2.f / (1.f + __expf(-lg));
  }
}

// PP[i,j] = (fnorm_i . fnorm_j) * 0.5*(W[i,j]+W[j,i]); upper-triangle only.
// Both W tiles (direct Wd + transposed Wt) are staged into LDS AT KERNEL
// START, coexisting with Asw/Bsw (no time-multiplex) -> their HBM latency
// drains under the MFMA K-loop; epilogue reads LDS only.
__global__ __launch_bounds__(256) void ppbuild_sym(const unsigned short* __restrict__ fnorm,
                                                   const float* __restrict__ W,
                                                   unsigned short* __restrict__ PP) {
  int bi, bj;
  tril_decode(blockIdx.x, bi, bj);
  const int i0 = bi * 64, j0 = bj * 64;

  __shared__ __align__(16) unsigned char shm[51200];
  unsigned short* Asw = (unsigned short*)shm;            // 8192 B
  unsigned short* Bsw = (unsigned short*)(shm + 8192);   // 8192 B
  unsigned short* OutD = (unsigned short*)shm;           // 9472 B (epilogue overlay)
  float (*Wt)[68] = (float(*)[68])(shm + 16384);         // 17408 B
  float (*Wd)[68] = (float(*)[68])(shm + 33792);         // 17408 B

  const int t = threadIdx.x;
  const int lane = t & 63;
  const int wv = t >> 6;
  const int wi = wv >> 1, wj = wv & 1;
  const int khalf = lane >> 5;

  // stage both W tiles coalesced into LDS (latency hides under K-loop)
  {
    const int jW = t >> 2, cbW = (t & 3) * 16;
    const float* srcT = W + (size_t)(j0 + jW) * NROWS + i0 + cbW;
    const float* srcD = W + (size_t)(i0 + jW) * NROWS + j0 + cbW;
#pragma unroll
    for (int q = 0; q < 4; ++q) {
      float4 vT = *(const float4*)(srcT + q * 4);
      float4 vD = *(const float4*)(srcD + q * 4);
      Wt[jW][cbW + q * 4 + 0] = vT.x; Wt[jW][cbW + q * 4 + 1] = vT.y;
      Wt[jW][cbW + q * 4 + 2] = vT.z; Wt[jW][cbW + q * 4 + 3] = vT.w;
      Wd[jW][cbW + q * 4 + 0] = vD.x; Wd[jW][cbW + q * 4 + 1] = vD.y;
      Wd[jW][cbW + q * 4 + 2] = vD.z; Wd[jW][cbW + q * 4 + 3] = vD.w;
    }
  }

  f32x16 acc;
#pragma unroll
  for (int r = 0; r < 16; ++r) acc[r] = 0.f;

  const int lrow = t >> 2;
  const int lgp = (t & 3) * 2;
  const int arow = wi * 32 + (lane & 31);
  const int brow = wj * 32 + (lane & 31);
#pragma unroll 1
  for (int c = 0; c < 4; ++c) {
    const unsigned short* sa = fnorm + (size_t)(i0 + lrow) * 256 + c * 64 + lgp * 8;
    const unsigned short* sb = fnorm + (size_t)(j0 + lrow) * 256 + c * 64 + lgp * 8;
    u16x8 va0 = *(const u16x8*)(sa);
    u16x8 va1 = *(const u16x8*)(sa + 8);
    u16x8 vb0 = *(const u16x8*)(sb);
    u16x8 vb1 = *(const u16x8*)(sb + 8);
    __syncthreads();
    int s0 = (lgp ^ (lrow & 7)) * 8;
    int s1 = ((lgp + 1) ^ (lrow & 7)) * 8;
    *(u16x8*)&Asw[lrow * 64 + s0] = va0;
    *(u16x8*)&Asw[lrow * 64 + s1] = va1;
    *(u16x8*)&Bsw[lrow * 64 + s0] = vb0;
    *(u16x8*)&Bsw[lrow * 64 + s1] = vb1;
    __syncthreads();
#pragma unroll
    for (int s = 0; s < 4; ++s) {
      int slot = s * 2 + khalf;
      bf16x8 a = *(const bf16x8*)&Asw[arow * 64 + ((slot ^ (arow & 7)) * 8)];
      bf16x8 b = *(const bf16x8*)&Bsw[brow * 64 + ((slot ^ (brow & 7)) * 8)];
      acc = __builtin_amdgcn_mfma_f32_32x32x16_bf16(a, b, acc, 0, 0, 0);
    }
  }

  __syncthreads();  // Asw/Bsw reads complete; Wt/Wd visible; OutD may overlay
  unsigned short pb[16];
#pragma unroll
  for (int r = 0; r < 16; ++r) {
    int rowl = (r & 3) + 8 * (r >> 2) + 4 * khalf;
    int coll = lane & 31;
    int il = wi * 32 + rowl, jl = wj * 32 + coll;
    float ws = 0.5f * (Wd[il][jl] + Wt[jl][il]);
    pb[r] = f2bf(acc[r] * ws);
  }
#pragma unroll
  for (int r = 0; r < 16; ++r) {
    int rowl = (r & 3) + 8 * (r >> 2) + 4 * khalf;
    int coll = lane & 31;
    OutD[(wi * 32 + rowl) * 74 + wj * 32 + coll] = pb[r];
  }
  __syncthreads();
  const int row = t >> 3;
  const int seg = t & 7;
#pragma unroll
  for (int q = 0; q < 2; ++q) {
    int rr = row + q * 32;
    const unsigned int* pd = (const unsigned int*)(OutD + rr * 74 + seg * 8);
    union { u16x8 v; unsigned int u[4]; } dd;
#pragma unroll
    for (int k = 0; k < 4; ++k) dd.u[k] = pd[k];
    *(u16x8*)(PP + (size_t)(i0 + rr) * NROWS + j0 + seg * 8) = dd.v;
  }
}

// One full iteration per launch: coef from fully-accumulated Zprev (int64
// fixed-point, order-independent => deterministic), 128x128 symmetric tile
// partials accumulated into Zacc via int64 atomics. Diagonal blocks zero
// Zzero for use two iterations later.
__global__ __launch_bounds__(256) void ppmv_atomic(
    const unsigned short* __restrict__ PP,
    const float* __restrict__ unary,
    const long long* __restrict__ Zprev,     // null on iteration 1
    const float* __restrict__ coef0,
    unsigned long long* __restrict__ Zacc,
    unsigned long long* __restrict__ Zzero) { // null on last iteration
  int bi, bj;
  tril64_decode(blockIdx.x, bi, bj);
  const int i0 = bi * 128, j0 = bj * 128;
  const int t = threadIdx.x;

  __shared__ __align__(16) unsigned short tile[128][132];  // 33792 B
  __shared__ float cj[128], ci[128];
  __shared__ float Tw[8][128];

  // issue PP tile loads into registers first (L3/HBM latency overlaps rest)
  const int r = t >> 1, h = (t & 1) * 64;
  u16x8 tv[8];
  {
    const unsigned short* src = PP + (size_t)(i0 + r) * NROWS + j0 + h;
#pragma unroll
    for (int q = 0; q < 8; ++q) tv[q] = *(const u16x8*)(src + q * 8);
  }
  // zero duty: diagonal band zeroes its 128 rows of the buffer accumulated
  // two iterations from now (untouched by anyone this iteration)
  if (bi == bj && Zzero != nullptr && t < 128) Zzero[i0 + t] = 0ull;
  // coef for this thread's assigned row
  {
    int myrow = (t < 128) ? (j0 + t) : (i0 + (t - 128));
    float c;
    if (Zprev) {
      float lg = unary[myrow] + (float)Zprev[myrow] * EINV;
      c = 1.f - 2.f / (1.f + __expf(-lg));
    } else {
      c = coef0[myrow];
    }
    if (t < 128) cj[t] = c;
    else ci[t - 128] = c;
  }
#pragma unroll
  for (int q = 0; q < 8; ++q) *(u16x8*)&tile[r][h + q * 8] = tv[q];
  __syncthreads();
  // row sums (D): matrix data straight from tv registers; coefs from LDS
  {
    float a = 0.f;
#pragma unroll
    for (int q = 0; q < 8; ++q) {
      u16x8 v = tv[q];
      float4 c0 = *(const float4*)&cj[h + q * 8];
      float4 c1 = *(const float4*)&cj[h + q * 8 + 4];
      a += bf2f(v[0]) * c0.x + bf2f(v[1]) * c0.y + bf2f(v[2]) * c0.z + bf2f(v[3]) * c0.w;
      a += bf2f(v[4]) * c1.x + bf2f(v[5]) * c1.y + bf2f(v[6]) * c1.z + bf2f(v[7]) * c1.w;
    }
    a += __shfl_xor(a, 1);
    if ((t & 1) == 0)
      atomicAdd(&Zacc[i0 + r], (unsigned long long)(long long)llrintf(a * ESCALE));
  }
  // col sums (T): thread owns 4 cols x 16 rows (ushort4 LDS reads)
  {
    const int c4 = (t & 31) * 4, rg = t >> 5;
    float a0 = 0.f, a1 = 0.f, a2 = 0.f, a3 = 0.f;
#pragma unroll
    for (int k = 0; k < 16; ++k) {
      int row = rg * 16 + k;
      ushort4 v = *(const ushort4*)&tile[row][c4];
      float s = ci[row];
      a0 += bf2f(v.x) * s; a1 += bf2f(v.y) * s;
      a2 += bf2f(v.z) * s; a3 += bf2f(v.w) * s;
    }
    Tw[rg][c4] = a0; Tw[rg][c4 + 1] = a1;
    Tw[rg][c4 + 2] = a2; Tw[rg][c4 + 3] = a3;
  }
  __syncthreads();
  if (t < 128 && bi != bj) {
    float s = ((Tw[0][t] + Tw[1][t]) + (Tw[2][t] + Tw[3][t])) +
              ((Tw[4][t] + Tw[5][t]) + (Tw[6][t] + Tw[7][t]));
    atomicAdd(&Zacc[j0 + t], (unsigned long long)(long long)llrintf(s * ESCALE));
  }
}

// final: lg = unary + Zfinal*EINV -> out
__global__ __launch_bounds__(256) void final_out(const long long* __restrict__ Z,
                                                 const float* __restrict__ unary,
                                                 float* __restrict__ out) {
  int row = blockIdx.x * 256 + threadIdx.x;
  out[row] = unary[row] + (float)Z[row] * EINV;
}

extern "C" void kernel_launch(void* const* d_in, const int* in_sizes, int n_in,
                              void* d_out, int out_size, void* d_ws, size_t ws_size,
                              hipStream_t stream) {
  const float* x   = (const float*)d_in[0];
  const float* W   = (const float*)d_in[1];
  const float* W1  = (const float*)d_in[2];
  const float* g1  = (const float*)d_in[4];
  const float* be1 = (const float*)d_in[5];
  const float* W2  = (const float*)d_in[6];
  const float* g2  = (const float*)d_in[8];
  const float* be2 = (const float*)d_in[9];
  const float* fcw = (const float*)d_in[10];
  const float* fcb = (const float*)d_in[11];
  float* out = (float*)d_out;

  char* ws = (char*)d_ws;
  unsigned short* hraw = (unsigned short*)(ws + 0);          // 8 MB (dead after gemm2)
  unsigned short* fraw = (unsigned short*)(ws + 8388608);    // 4 MB
  float* pS1   = (float*)(ws + 12582912);                    // 256 KB
  float* pQ1   = (float*)(ws + 12845056);                    // 256 KB
  float* pS2   = (float*)(ws + 13107200);                    // 128 KB
  float* pQ2   = (float*)(ws + 13238272);                    // 128 KB
  float2* ab1  = (float2*)(ws + 13369344);                   // 4 KB
  float2* ab2  = (float2*)(ws + 13373440);                   // 2 KB
  unsigned short* fnorm = (unsigned short*)(ws + 13375488);  // 4 MB
  float* unary = (float*)(ws + 17569792);
  float* coefA = (float*)(ws + 17602560);
  unsigned short* xb  = (unsigned short*)(ws + 26056704);    // 2 MB
  unsigned short* w1b = (unsigned short*)(ws + 28153856);    // 128 KB
  unsigned short* w2b = (unsigned short*)(ws + 28284928);    // 256 KB
  unsigned short* PP  = (unsigned short*)(ws + 28547072);    // 128 MB -> 162764800
  unsigned long long* Z0 = (unsigned long long*)(ws + 162764800);  // 64 KB
  unsigned long long* Z1 = (unsigned long long*)(ws + 162830336);  // 64 KB
  unsigned long long* Z2 = (unsigned long long*)(ws + 162895872);  // 64 KB
  if (ws_size < (size_t)162961408) return;
  unsigned long long* Z[3] = {Z0, Z1, Z2};

  // casts (one kernel; also zeroes Z0 for iteration 1)
  cast3<<<608, 256, 0, stream>>>(x, W1, W2, xb, w1b, w2b, Z0);
  // layer 1: hraw = x @ W1^T (bf16 out + fused col stats); BN params
  gemm_bt_mfma_stats<<<dim3(128, 8), 256, 0, stream>>>(xb, w1b, nullptr, hraw,
                                                       pS1, pQ1, 512, 128);
  bn_finalize<<<2, 256, 0, stream>>>(pS1, pQ1, g1, be1, ab1, 512);
  // layer 2: fraw = BN1(hraw) @ W2^T — bn_apply fused into A-staging
  gemm_bt_mfma_stats<<<dim3(128, 4), 256, 0, stream>>>(hraw, w2b, ab1, fraw,
                                                       pS2, pQ2, 256, 512);
  bn_finalize<<<1, 256, 0, stream>>>(pS2, pQ2, g2, be2, ab2, 256);
  bn_rowfn<<<2048, 256, 0, stream>>>(fraw, ab2, fcw, fcb, fnorm, unary, coefA);
  // PP upper triangle (W staged through coexisting LDS, latency under K-loop)
  ppbuild_sym<<<8256, 256, 0, stream>>>(fnorm, W, PP);
  // 10 iterations, ONE kernel each (int64 fixed-point atomics: deterministic;
  // no per-iter reduce kernel, no grid.sync (~125 us/sync, round 8), no
  // redundant fp32 fold (65x fan-in, round 11))
  for (int it = 1; it <= NITER; ++it) {
    const long long* zp = (it == 1) ? nullptr : (const long long*)Z[(it + 1) % 3];
    unsigned long long* za = Z[(it - 1) % 3];
    unsigned long long* zz = (it < NITER) ? Z[it % 3] : nullptr;
    ppmv_atomic<<<2080, 256, 0, stream>>>(PP, unary, zp, coefA, za, zz);
  }
  final_out<<<32, 256, 0, stream>>>((const long long*)Z[(NITER - 1) % 3], unary, out);
}

// Round 17
// 285.398 us; speedup vs baseline: 1.0485x; 1.0485x over previous
//
#include <hip/hip_runtime.h>
#include <hip/hip_bf16.h>

#define NROWS 8192
#define NITER 10
#define ESCALE 1048576.0f          // 2^20 fixed-point scale for E partials
#define EINV   (1.0f / 1048576.0f)

typedef __attribute__((ext_vector_type(8))) short bf16x8;
typedef __attribute__((ext_vector_type(8))) unsigned short u16x8;
typedef __attribute__((ext_vector_type(16))) float f32x16;

__device__ __forceinline__ float bf2f(unsigned short u) {
  union { float f; unsigned int i; } c; c.i = ((unsigned int)u) << 16; return c.f;
}
__device__ __forceinline__ unsigned short f2bf(float f) {
  unsigned int x = __float_as_uint(f);
  unsigned int r = (x + 0x7FFFu + ((x >> 16) & 1u)) >> 16;
  return (unsigned short)r;
}

// tril inversion, 128-wide grid (64x64 tiles) for ppbuild
#define TRIS(b) ((b) * (257 - (b)) / 2)
__device__ __forceinline__ void tril_decode(int L, int& bi, int& bj) {
  int b = (int)((257.0f - sqrtf((float)(66049 - 8 * L))) * 0.5f);
  if (b > 127) b = 127;
  if (b < 0) b = 0;
  while (b < 127 && TRIS(b + 1) <= L) ++b;
  while (b > 0 && TRIS(b) > L) --b;
  bi = b;
  bj = b + (L - TRIS(b));
}

// tril inversion, 64-wide grid (128x128 tiles) for ppmv
#define TRIS64(b) ((b) * (129 - (b)) / 2)
__device__ __forceinline__ void tril64_decode(int L, int& bi, int& bj) {
  int b = (int)((129.0f - sqrtf((float)(16641 - 8 * L))) * 0.5f);
  if (b > 63) b = 63;
  if (b < 0) b = 0;
  while (b < 63 && TRIS64(b + 1) <= L) ++b;
  while (b > 0 && TRIS64(b) > L) --b;
  bi = b;
  bj = b + (L - TRIS64(b));
}

// casts x, W1, W2 to bf16 (8 elems/thread) and zeroes Z0 (it-1 accumulator)
__global__ __launch_bounds__(256) void cast3(const float* __restrict__ x,
                                             const float* __restrict__ W1,
                                             const float* __restrict__ W2,
                                             unsigned short* __restrict__ xb,
                                             unsigned short* __restrict__ w1b,
                                             unsigned short* __restrict__ w2b,
                                             unsigned long long* __restrict__ Z0) {
  int idx = blockIdx.x * 256 + threadIdx.x;
  if (idx < NROWS) Z0[idx] = 0ull;
  const float* src; unsigned short* dst; int l;
  if (idx < 131072) { src = x; dst = xb; l = idx; }
  else if (idx < 139264) { src = W1; dst = w1b; l = idx - 131072; }
  else if (idx < 155648) { src = W2; dst = w2b; l = idx - 139264; }
  else return;
  const float4* p = (const float4*)src + (size_t)l * 2;
  float4 a = p[0], b = p[1];
  u16x8 o;
  o[0] = f2bf(a.x); o[1] = f2bf(a.y); o[2] = f2bf(a.z); o[3] = f2bf(a.w);
  o[4] = f2bf(b.x); o[5] = f2bf(b.y); o[6] = f2bf(b.z); o[7] = f2bf(b.w);
  *(u16x8*)(dst + (size_t)l * 8) = o;
}

// C[M,NN] = A[M,K] @ B[NN,K]^T (bf16 in, bf16 out) + fused per-column
// partial BN stats (sum, sumsq) from the fp32 accumulators.
__global__ __launch_bounds__(256) void gemm_bt_mfma_stats(
    const unsigned short* __restrict__ A, const unsigned short* __restrict__ B,
    unsigned short* __restrict__ Cb, float* __restrict__ pS, float* __restrict__ pQ,
    int NN, int K) {
  __shared__ __align__(16) unsigned short Asw[4096];
  __shared__ __align__(16) unsigned short Bsw[4096];
  __shared__ float Sarr[4][64], Qarr[4][64];
  const int i0 = blockIdx.x * 64, j0 = blockIdx.y * 64;
  const int t = threadIdx.x;
  const int lane = t & 63;
  const int wv = t >> 6;
  const int wi = wv >> 1, wj = wv & 1;
  const int khalf = lane >> 5;

  f32x16 acc;
#pragma unroll
  for (int r = 0; r < 16; ++r) acc[r] = 0.f;

  const int lrow = t >> 2;
  const int lgp = (t & 3) * 2;
  const int arow = wi * 32 + (lane & 31);
  const int brow = wj * 32 + (lane & 31);
  const int nc = K >> 6;
#pragma unroll 1
  for (int c = 0; c < nc; ++c) {
    const unsigned short* sa = A + (size_t)(i0 + lrow) * K + c * 64 + lgp * 8;
    const unsigned short* sb = B + (size_t)(j0 + lrow) * K + c * 64 + lgp * 8;
    u16x8 va0 = *(const u16x8*)(sa);
    u16x8 va1 = *(const u16x8*)(sa + 8);
    u16x8 vb0 = *(const u16x8*)(sb);
    u16x8 vb1 = *(const u16x8*)(sb + 8);
    __syncthreads();
    int s0 = (lgp ^ (lrow & 7)) * 8;
    int s1 = ((lgp + 1) ^ (lrow & 7)) * 8;
    *(u16x8*)&Asw[lrow * 64 + s0] = va0;
    *(u16x8*)&Asw[lrow * 64 + s1] = va1;
    *(u16x8*)&Bsw[lrow * 64 + s0] = vb0;
    *(u16x8*)&Bsw[lrow * 64 + s1] = vb1;
    __syncthreads();
#pragma unroll
    for (int s = 0; s < 4; ++s) {
      int slot = s * 2 + khalf;
      bf16x8 a = *(const bf16x8*)&Asw[arow * 64 + ((slot ^ (arow & 7)) * 8)];
      bf16x8 b = *(const bf16x8*)&Bsw[brow * 64 + ((slot ^ (brow & 7)) * 8)];
      acc = __builtin_amdgcn_mfma_f32_32x32x16_bf16(a, b, acc, 0, 0, 0);
    }
  }
  // epilogue: bf16 store + per-lane column stats (16 rows of column coll)
  float s = 0.f, q = 0.f;
#pragma unroll
  for (int r = 0; r < 16; ++r) {
    int rowl = (r & 3) + 8 * (r >> 2) + 4 * khalf;
    int coll = lane & 31;
    float v = acc[r];
    s += v; q += v * v;
    Cb[(size_t)(i0 + wi * 32 + rowl) * NN + j0 + wj * 32 + coll] = f2bf(v);
  }
  Sarr[wv][lane] = s;
  Qarr[wv][lane] = q;
  __syncthreads();
  if (t < 64) {  // column c of block: fold 4 deterministic contributions
    int wjc = t >> 5, coll = t & 31;
    float st = (Sarr[wjc][coll] + Sarr[wjc][coll + 32]) +
               (Sarr[wjc + 2][coll] + Sarr[wjc + 2][coll + 32]);
    float qt = (Qarr[wjc][coll] + Qarr[wjc][coll + 32]) +
               (Qarr[wjc + 2][coll] + Qarr[wjc + 2][coll + 32]);
    pS[(size_t)blockIdx.x * NN + j0 + t] = st;
    pQ[(size_t)blockIdx.x * NN + j0 + t] = qt;
  }
}

// fold 128 row-block partial stats -> per-column scale/shift
__global__ void bn_finalize(const float* __restrict__ pS, const float* __restrict__ pQ,
                            const float* __restrict__ g, const float* __restrict__ be,
                            float2* __restrict__ ab, int C) {
  int c = blockIdx.x * 256 + threadIdx.x;
  if (c >= C) return;
  float s = 0.f, q = 0.f;
  for (int r = 0; r < 128; ++r) { s += pS[(size_t)r * C + c]; q += pQ[(size_t)r * C + c]; }
  const float invM = 1.f / 8192.f;
  float mu = s * invM;
  float var = q * invM - mu * mu;
  float rstd = rsqrtf(var + 1e-5f);
  float a = g[c] * rstd;
  ab[c] = make_float2(a, be[c] - mu * a);
}

// hb = leaky_relu(a*hraw + b), bf16 -> bf16, 8 elems/thread
__global__ __launch_bounds__(256) void bn_apply(const unsigned short* __restrict__ hraw,
                                                const float2* __restrict__ ab,
                                                unsigned short* __restrict__ hb,
                                                int Cmask) {
  size_t idx = (size_t)blockIdx.x * 256 + threadIdx.x;
  u16x8 v = *(const u16x8*)(hraw + idx * 8);
  int cb = (int)((idx * 8) & (size_t)Cmask);
  u16x8 o;
#pragma unroll
  for (int k = 0; k < 8; ++k) {
    float2 a = ab[cb + k];
    float r = a.x * bf2f(v[k]) + a.y;
    r = r >= 0.f ? r : 0.01f * r;
    o[k] = f2bf(r);
  }
  *(u16x8*)(hb + idx * 8) = o;
}

// fused: feats-BN + leaky + row norm + fc logit; writes fnorm bf16, unary, coef0
__global__ __launch_bounds__(256) void bn_rowfn(const unsigned short* __restrict__ fraw,
                                                const float2* __restrict__ ab,
                                                const float* __restrict__ fcw,
                                                const float* __restrict__ fcb,
                                                unsigned short* __restrict__ fnorm,
                                                float* __restrict__ unary,
                                                float* __restrict__ coef0) {
  const int lane = threadIdx.x & 63;
  const int row = blockIdx.x * 4 + (threadIdx.x >> 6);
  ushort4 v4 = *(const ushort4*)(fraw + (size_t)row * 256 + lane * 4);
  float4 w = *(const float4*)(fcw + lane * 4);
  int c = lane * 4;
  float2 a0 = ab[c], a1 = ab[c + 1], a2 = ab[c + 2], a3 = ab[c + 3];
  float f0 = a0.x * bf2f(v4.x) + a0.y; f0 = f0 >= 0.f ? f0 : 0.01f * f0;
  float f1 = a1.x * bf2f(v4.y) + a1.y; f1 = f1 >= 0.f ? f1 : 0.01f * f1;
  float f2 = a2.x * bf2f(v4.z) + a2.y; f2 = f2 >= 0.f ? f2 : 0.01f * f2;
  float f3 = a3.x * bf2f(v4.w) + a3.y; f3 = f3 >= 0.f ? f3 : 0.01f * f3;
  float ssq = f0 * f0 + f1 * f1 + f2 * f2 + f3 * f3;
  float dot = f0 * w.x + f1 * w.y + f2 * w.z + f3 * w.w;
#pragma unroll
  for (int o = 32; o; o >>= 1) { ssq += __shfl_xor(ssq, o); dot += __shfl_xor(dot, o); }
  float rfn = rsqrtf(ssq);
  *(ushort4*)(fnorm + (size_t)row * 256 + lane * 4) =
      make_ushort4(f2bf(f0 * rfn), f2bf(f1 * rfn), f2bf(f2 * rfn), f2bf(f3 * rfn));
  if (lane == 0) {
    float lg = dot + fcb[0];
    unary[row] = lg;
    coef0[row] = 1.f - 2.f / (1.f + __expf(-lg));
  }
}

// PP[i,j] = (fnorm_i . fnorm_j) * 0.5*(W[i,j]+W[j,i]); upper-triangle only.
// W tiles (transposed + direct) are PREFETCHED into registers before the
// MFMA K-loop so their HBM latency hides under it (async-STAGE split).
__global__ __launch_bounds__(256) void ppbuild_sym(const unsigned short* __restrict__ fnorm,
                                                   const float* __restrict__ W,
                                                   unsigned short* __restrict__ PP) {
  int bi, bj;
  tril_decode(blockIdx.x, bi, bj);
  const int i0 = bi * 64, j0 = bj * 64;

  __shared__ __align__(16) unsigned char shm[18944];
  unsigned short* Asw = (unsigned short*)shm;
  unsigned short* Bsw = (unsigned short*)shm + 4736;
  float (*Wt)[68] = (float(*)[68])shm;
  unsigned short* OutD = (unsigned short*)shm;

  const int t = threadIdx.x;
  const int lane = t & 63;
  const int wv = t >> 6;
  const int wi = wv >> 1, wj = wv & 1;
  const int khalf = lane >> 5;

  // ---- prefetch W into registers (latency hides under K-loop) ----
  const int jW = t >> 2, cbW = (t & 3) * 16;
  const float* srcT = W + (size_t)(j0 + jW) * NROWS + i0 + cbW;
  float4 wtv[4];
#pragma unroll
  for (int q = 0; q < 4; ++q) wtv[q] = *(const float4*)(srcT + q * 4);
  float wdv[16];
#pragma unroll
  for (int r = 0; r < 16; ++r) {
    int rowl = (r & 3) + 8 * (r >> 2) + 4 * khalf;
    wdv[r] = W[(size_t)(i0 + wi * 32 + rowl) * NROWS + (j0 + wj * 32 + (lane & 31))];
  }
  __builtin_amdgcn_sched_barrier(0);  // keep the 20 loads issued up-front

  f32x16 acc;
#pragma unroll
  for (int r = 0; r < 16; ++r) acc[r] = 0.f;

  const int lrow = t >> 2;
  const int lgp = (t & 3) * 2;
  const int arow = wi * 32 + (lane & 31);
  const int brow = wj * 32 + (lane & 31);
#pragma unroll 1
  for (int c = 0; c < 4; ++c) {
    const unsigned short* sa = fnorm + (size_t)(i0 + lrow) * 256 + c * 64 + lgp * 8;
    const unsigned short* sb = fnorm + (size_t)(j0 + lrow) * 256 + c * 64 + lgp * 8;
    u16x8 va0 = *(const u16x8*)(sa);
    u16x8 va1 = *(const u16x8*)(sa + 8);
    u16x8 vb0 = *(const u16x8*)(sb);
    u16x8 vb1 = *(const u16x8*)(sb + 8);
    __syncthreads();
    int s0 = (lgp ^ (lrow & 7)) * 8;
    int s1 = ((lgp + 1) ^ (lrow & 7)) * 8;
    *(u16x8*)&Asw[lrow * 64 + s0] = va0;
    *(u16x8*)&Asw[lrow * 64 + s1] = va1;
    *(u16x8*)&Bsw[lrow * 64 + s0] = vb0;
    *(u16x8*)&Bsw[lrow * 64 + s1] = vb1;
    __syncthreads();
#pragma unroll
    for (int s = 0; s < 4; ++s) {
      int slot = s * 2 + khalf;
      bf16x8 a = *(const bf16x8*)&Asw[arow * 64 + ((slot ^ (arow & 7)) * 8)];
      bf16x8 b = *(const bf16x8*)&Bsw[brow * 64 + ((slot ^ (brow & 7)) * 8)];
      acc = __builtin_amdgcn_mfma_f32_32x32x16_bf16(a, b, acc, 0, 0, 0);
    }
  }

  __syncthreads();   // done reading Asw/Bsw; LDS becomes Wt
  {
#pragma unroll
    for (int q = 0; q < 4; ++q) {
      Wt[jW][cbW + q * 4 + 0] = wtv[q].x; Wt[jW][cbW + q * 4 + 1] = wtv[q].y;
      Wt[jW][cbW + q * 4 + 2] = wtv[q].z; Wt[jW][cbW + q * 4 + 3] = wtv[q].w;
    }
  }
  __syncthreads();
  unsigned short pb[16];
#pragma unroll
  for (int r = 0; r < 16; ++r) {
    int rowl = (r & 3) + 8 * (r >> 2) + 4 * khalf;
    int coll = lane & 31;
    int il = wi * 32 + rowl, jl = wj * 32 + coll;
    float ws = 0.5f * (wdv[r] + Wt[jl][il]);
    pb[r] = f2bf(acc[r] * ws);
  }
  __syncthreads();
#pragma unroll
  for (int r = 0; r < 16; ++r) {
    int rowl = (r & 3) + 8 * (r >> 2) + 4 * khalf;
    int coll = lane & 31;
    OutD[(wi * 32 + rowl) * 74 + wj * 32 + coll] = pb[r];
  }
  __syncthreads();
  const int row = t >> 3;
  const int seg = t & 7;
#pragma unroll
  for (int q = 0; q < 2; ++q) {
    int rr = row + q * 32;
    const unsigned int* pd = (const unsigned int*)(OutD + rr * 74 + seg * 8);
    union { u16x8 v; unsigned int u[4]; } dd;
#pragma unroll
    for (int k = 0; k < 4; ++k) dd.u[k] = pd[k];
    *(u16x8*)(PP + (size_t)(i0 + rr) * NROWS + j0 + seg * 8) = dd.v;
  }
}

// One full iteration per launch: coef from fully-accumulated Zprev (int64
// fixed-point, order-independent => deterministic), 128x128 symmetric tile
// partials accumulated into Zacc via int64 atomics. Diagonal blocks zero
// Zzero for use two iterations later. Row pass reads the tile from the
// registers it was loaded into; LDS tile serves only the transposed pass.
__global__ __launch_bounds__(256) void ppmv_atomic(
    const unsigned short* __restrict__ PP,
    const float* __restrict__ unary,
    const long long* __restrict__ Zprev,     // null on iteration 1
    const float* __restrict__ coef0,
    unsigned long long* __restrict__ Zacc,
    unsigned long long* __restrict__ Zzero) { // null on last iteration
  int bi, bj;
  tril64_decode(blockIdx.x, bi, bj);
  const int i0 = bi * 128, j0 = bj * 128;
  const int t = threadIdx.x;

  __shared__ __align__(16) unsigned short tile[128][132];  // 33792 B
  __shared__ float cj[128], ci[128];
  __shared__ float Tw[8][128];

  // issue PP tile loads into registers first (L3/HBM latency overlaps rest)
  const int r = t >> 1, h = (t & 1) * 64;
  u16x8 tv[8];
  {
    const unsigned short* src = PP + (size_t)(i0 + r) * NROWS + j0 + h;
#pragma unroll
    for (int q = 0; q < 8; ++q) tv[q] = *(const u16x8*)(src + q * 8);
  }
  // zero duty: diagonal band zeroes its 128 rows of the buffer accumulated
  // two iterations from now (untouched by anyone this iteration)
  if (bi == bj && Zzero != nullptr && t < 128) Zzero[i0 + t] = 0ull;
  // coef for this thread's assigned row
  {
    int myrow = (t < 128) ? (j0 + t) : (i0 + (t - 128));
    float c;
    if (Zprev) {
      float lg = unary[myrow] + (float)Zprev[myrow] * EINV;
      c = 1.f - 2.f / (1.f + __expf(-lg));
    } else {
      c = coef0[myrow];
    }
    if (t < 128) cj[t] = c;
    else ci[t - 128] = c;
  }
#pragma unroll
  for (int q = 0; q < 8; ++q) *(u16x8*)&tile[r][h + q * 8] = tv[q];
  __syncthreads();
  // row sums (D): matrix data straight from tv registers; coefs from LDS
  {
    float a = 0.f;
#pragma unroll
    for (int q = 0; q < 8; ++q) {
      u16x8 v = tv[q];
      float4 c0 = *(const float4*)&cj[h + q * 8];
      float4 c1 = *(const float4*)&cj[h + q * 8 + 4];
      a += bf2f(v[0]) * c0.x + bf2f(v[1]) * c0.y + bf2f(v[2]) * c0.z + bf2f(v[3]) * c0.w;
      a += bf2f(v[4]) * c1.x + bf2f(v[5]) * c1.y + bf2f(v[6]) * c1.z + bf2f(v[7]) * c1.w;
    }
    a += __shfl_xor(a, 1);
    if ((t & 1) == 0)
      atomicAdd(&Zacc[i0 + r], (unsigned long long)(long long)llrintf(a * ESCALE));
  }
  // col sums (T): thread owns 4 cols x 16 rows (ushort4 LDS reads)
  {
    const int c4 = (t & 31) * 4, rg = t >> 5;
    float a0 = 0.f, a1 = 0.f, a2 = 0.f, a3 = 0.f;
#pragma unroll
    for (int k = 0; k < 16; ++k) {
      int row = rg * 16 + k;
      ushort4 v = *(const ushort4*)&tile[row][c4];
      float s = ci[row];
      a0 += bf2f(v.x) * s; a1 += bf2f(v.y) * s;
      a2 += bf2f(v.z) * s; a3 += bf2f(v.w) * s;
    }
    Tw[rg][c4] = a0; Tw[rg][c4 + 1] = a1;
    Tw[rg][c4 + 2] = a2; Tw[rg][c4 + 3] = a3;
  }
  __syncthreads();
  if (t < 128 && bi != bj) {
    float s = ((Tw[0][t] + Tw[1][t]) + (Tw[2][t] + Tw[3][t])) +
              ((Tw[4][t] + Tw[5][t]) + (Tw[6][t] + Tw[7][t]));
    atomicAdd(&Zacc[j0 + t], (unsigned long long)(long long)llrintf(s * ESCALE));
  }
}

// final: lg = unary + Zfinal*EINV -> out
__global__ __launch_bounds__(256) void final_out(const long long* __restrict__ Z,
                                                 const float* __restrict__ unary,
                                                 float* __restrict__ out) {
  int row = blockIdx.x * 256 + threadIdx.x;
  out[row] = unary[row] + (float)Z[row] * EINV;
}

extern "C" void kernel_launch(void* const* d_in, const int* in_sizes, int n_in,
                              void* d_out, int out_size, void* d_ws, size_t ws_size,
                              hipStream_t stream) {
  const float* x   = (const float*)d_in[0];
  const float* W   = (const float*)d_in[1];
  const float* W1  = (const float*)d_in[2];
  const float* g1  = (const float*)d_in[4];
  const float* be1 = (const float*)d_in[5];
  const float* W2  = (const float*)d_in[6];
  const float* g2  = (const float*)d_in[8];
  const float* be2 = (const float*)d_in[9];
  const float* fcw = (const float*)d_in[10];
  const float* fcb = (const float*)d_in[11];
  float* out = (float*)d_out;

  char* ws = (char*)d_ws;
  unsigned short* hraw = (unsigned short*)(ws + 0);          // 8 MB (dead after bn_apply)
  unsigned short* fraw = (unsigned short*)(ws + 8388608);    // 4 MB
  float* pS1   = (float*)(ws + 12582912);                    // 256 KB
  float* pQ1   = (float*)(ws + 12845056);                    // 256 KB
  float* pS2   = (float*)(ws + 13107200);                    // 128 KB
  float* pQ2   = (float*)(ws + 13238272);                    // 128 KB
  float2* ab1  = (float2*)(ws + 13369344);                   // 4 KB
  float2* ab2  = (float2*)(ws + 13373440);                   // 2 KB
  unsigned short* fnorm = (unsigned short*)(ws + 13375488);  // 4 MB
  float* unary = (float*)(ws + 17569792);
  float* coefA = (float*)(ws + 17602560);
  unsigned short* hb  = (unsigned short*)(ws + 17668096);    // 8 MB
  unsigned short* xb  = (unsigned short*)(ws + 26056704);    // 2 MB
  unsigned short* w1b = (unsigned short*)(ws + 28153856);    // 128 KB
  unsigned short* w2b = (unsigned short*)(ws + 28284928);    // 256 KB
  unsigned short* PP  = (unsigned short*)(ws + 28547072);    // 128 MB -> 162764800
  unsigned long long* Z0 = (unsigned long long*)(ws + 162764800);  // 64 KB
  unsigned long long* Z1 = (unsigned long long*)(ws + 162830336);  // 64 KB
  unsigned long long* Z2 = (unsigned long long*)(ws + 162895872);  // 64 KB
  if (ws_size < (size_t)162961408) return;
  unsigned long long* Z[3] = {Z0, Z1, Z2};

  // casts (one kernel; also zeroes Z0 for iteration 1)
  cast3<<<608, 256, 0, stream>>>(x, W1, W2, xb, w1b, w2b, Z0);
  // layer 1: hraw = x @ W1^T (bf16 out + fused col stats); BN; leaky -> hb
  gemm_bt_mfma_stats<<<dim3(128, 8), 256, 0, stream>>>(xb, w1b, hraw, pS1, pQ1, 512, 128);
  bn_finalize<<<2, 256, 0, stream>>>(pS1, pQ1, g1, be1, ab1, 512);
  bn_apply<<<2048, 256, 0, stream>>>(hraw, ab1, hb, 511);
  // layer 2: fraw = hb @ W2^T (bf16 out + fused col stats); BN+rowfn fused
  gemm_bt_mfma_stats<<<dim3(128, 4), 256, 0, stream>>>(hb, w2b, fraw, pS2, pQ2, 256, 512);
  bn_finalize<<<1, 256, 0, stream>>>(pS2, pQ2, g2, be2, ab2, 256);
  bn_rowfn<<<2048, 256, 0, stream>>>(fraw, ab2, fcw, fcb, fnorm, unary, coefA);
  // PP upper triangle (W prefetched into regs, latency under MFMA K-loop)
  ppbuild_sym<<<8256, 256, 0, stream>>>(fnorm, W, PP);
  // 10 iterations, ONE kernel each (int64 fixed-point atomics: deterministic;
  // no per-iter reduce kernel, no grid.sync (~125 us/sync, round 8), no
  // redundant fp32 fold (65x fan-in, round 11))
  for (int it = 1; it <= NITER; ++it) {
    const long long* zp = (it == 1) ? nullptr : (const long long*)Z[(it + 1) % 3];
    unsigned long long* za = Z[(it - 1) % 3];
    unsigned long long* zz = (it < NITER) ? Z[it % 3] : nullptr;
    ppmv_atomic<<<2080, 256, 0, stream>>>(PP, unary, zp, coefA, za, zz);
  }
  final_out<<<32, 256, 0, stream>>>((const long long*)Z[(NITER - 1) % 3], unary, out);
}